// Round 4
// baseline (274.814 us; speedup 1.0000x reference)
//
#include <hip/hip_runtime.h>

#define NB 32
#define NL 6
#define NR 8
#define NH 64
#define NTRAJ 262144                 // 8^6
#define F4_PER_B (NTRAJ * NL / 4)    // 393216 float4 per batch element
// out shape: (NB, NTRAJ, NL) fp32, flat idx = b*NTRAJ*NL + n*NL + l

// ============================================================================
// MEASUREMENT ROUND: scatter_kernel is launched 3x (idempotent, same values).
// S = (dur_this - dur_prev) / 2 isolates the scatter's true cost, which is
// invisible in the top-5 counters (harness poison fills dominate at ~120us).
// If S ~= 35us the scatter is at its 201MB write roofline and the session is
// done; if S >= 55us there is real headroom to chase next round.
// ============================================================================

// Kernel 1: q0[b][l][r] = W3[0] . relu(W2 @ relu(W1 @ [rp[l,r,0], phi[b,l]] + b1) + b2) + b3[0]
__global__ __launch_bounds__(64) void q0_kernel(
    const float* __restrict__ phi,   // (B, L)
    const float* __restrict__ rp,    // (L, R, 1)
    const float* __restrict__ W1,    // (H, 2)
    const float* __restrict__ b1,    // (H)
    const float* __restrict__ W2,    // (H, H)
    const float* __restrict__ b2,    // (H)
    const float* __restrict__ W3,    // (6, H) -> row 0
    const float* __restrict__ b3,    // (6)
    float* __restrict__ q0)          // (B, L, R) flat
{
    const int bid = blockIdx.x;      // = (b*NL + l)*NR + r
    const int r  = bid & 7;
    const int bl = bid >> 3;         // b*NL + l
    const int l  = bl % NL;
    const int h  = threadIdx.x;      // 0..63

    const float x = rp[l * NR + r];  // Z==1
    const float p = phi[bl];

    float h1 = fmaf(W1[h * 2 + 0], x, fmaf(W1[h * 2 + 1], p, b1[h]));
    h1 = fmaxf(h1, 0.0f);

    __shared__ float s_h1[NH];
    s_h1[h] = h1;
    __syncthreads();

    float acc = b2[h];
    const float* w2row = W2 + h * NH;
    #pragma unroll
    for (int k = 0; k < NH; ++k) acc = fmaf(w2row[k], s_h1[k], acc);
    const float h2 = fmaxf(acc, 0.0f);

    float v = W3[h] * h2;
    #pragma unroll
    for (int off = 32; off > 0; off >>= 1)
        v += __shfl_down(v, off, 64);

    if (h == 0) q0[bid] = v + b3[0];
}

// Kernel 2: out[b][n][l] = q0[b][l][(n >> 3l) & 7]. Identical to round 3.
__global__ __launch_bounds__(256) void scatter_kernel(
    const float* __restrict__ q0,    // (B, L, R)
    float4* __restrict__ out4)       // (B, NTRAJ, L) viewed as float4
{
    __shared__ float s[NL * NR];     // 48 floats for this block's b
    const int b   = blockIdx.y;
    const int tid = threadIdx.x;

    if (tid < NL * NR) s[tid] = q0[b * NL * NR + tid];
    __syncthreads();

    float4* __restrict__ base = out4 + (size_t)b * F4_PER_B
                                     + (size_t)blockIdx.x * 8192;
    const unsigned ubase = blockIdx.x * 8192u + tid;

    #pragma unroll 4
    for (int j = 0; j < 32; ++j) {
        const unsigned u = ubase + j * 256u;  // float4 index within b
        const unsigned k = u / 3u;            // pair index -> n = 2k (magic-mul)
        const unsigned m = u - 3u * k;        // position in the 12-float group

        const float2 v0 = ((const float2*)s)[k & 3u];   // s[d0], s[d0+1]
        const float  v1 = s[ 8 + ((k >>  2) & 7u)];
        const float  v2 = s[16 + ((k >>  5) & 7u)];
        const float  v3 = s[24 + ((k >>  8) & 7u)];
        const float  v4 = s[32 + ((k >> 11) & 7u)];
        const float  v5 = s[40 + ((k >> 14) & 7u)];

        float4 val;
        val.x = (m == 0) ? v0.x : ((m == 1) ? v4   : v2);
        val.y = (m == 0) ? v1   : ((m == 1) ? v5   : v3);
        val.z = (m == 0) ? v2   : ((m == 1) ? v0.y : v4);
        val.w = (m == 0) ? v3   : ((m == 1) ? v1   : v5);

        base[j * 256 + tid] = val;
    }
}

extern "C" void kernel_launch(void* const* d_in, const int* in_sizes, int n_in,
                              void* d_out, int out_size, void* d_ws, size_t ws_size,
                              hipStream_t stream) {
    const float* phi = (const float*)d_in[0];  // (32, 6)
    const float* rp  = (const float*)d_in[1];  // (6, 8, 1)
    const float* W1  = (const float*)d_in[2];  // (64, 2)
    const float* b1  = (const float*)d_in[3];  // (64,)
    const float* W2  = (const float*)d_in[4];  // (64, 64)
    const float* b2  = (const float*)d_in[5];  // (64,)
    const float* W3  = (const float*)d_in[6];  // (6, 64)
    const float* b3  = (const float*)d_in[7];  // (6,)
    float* out = (float*)d_out;
    float* q0  = (float*)d_ws;                 // 1536 floats = 6 KB

    q0_kernel<<<NB * NL * NR, 64, 0, stream>>>(phi, rp, W1, b1, W2, b2, W3, b3, q0);

    dim3 grid(48, NB);
    // Launched 3x ON PURPOSE (idempotent): timing probe to isolate the
    // scatter's cost from the ~150us of harness resets inside the timed
    // window. Revert to a single launch once S is known.
    scatter_kernel<<<grid, 256, 0, stream>>>(q0, (float4*)out);
    scatter_kernel<<<grid, 256, 0, stream>>>(q0, (float4*)out);
    scatter_kernel<<<grid, 256, 0, stream>>>(q0, (float4*)out);
}

// Round 5
// 214.187 us; speedup vs baseline: 1.2831x; 1.2831x over previous
//
#include <hip/hip_runtime.h>

#define NB 32
#define NL 6
#define NR 8
#define NH 64
#define NTRAJ 262144                 // 8^6
#define F4_PER_B (NTRAJ * NL / 4)    // 393216 float4 per batch element
// out shape: (NB, NTRAJ, NL) fp32, flat idx = b*NTRAJ*NL + n*NL + l

// ============================================================================
// ROOFLINE NOTE (round-4 probe): triple-launch delta gave S ~= 30.1 us per
// scatter dispatch vs a 201.3MB / 6.65TB/s = 30.3 us write floor (the same
// achievable BW the harness fillBuffer hits on this buffer). The scatter IS
// the roofline; the rest of dur_us (~180us) is harness poison fills + resets
// inside the timed window, not kernel-controllable.
// ============================================================================

// Kernel 1: q0[b][l][r] = W3[0] . relu(W2 @ relu(W1 @ [rp[l,r,0], phi[b,l]] + b1) + b2) + b3[0]
// One block (1 wave) per (b,l,r). 1536 blocks, ~5 us.
__global__ __launch_bounds__(64) void q0_kernel(
    const float* __restrict__ phi,   // (B, L)
    const float* __restrict__ rp,    // (L, R, 1)
    const float* __restrict__ W1,    // (H, 2)
    const float* __restrict__ b1,    // (H)
    const float* __restrict__ W2,    // (H, H)
    const float* __restrict__ b2,    // (H)
    const float* __restrict__ W3,    // (6, H) -> row 0
    const float* __restrict__ b3,    // (6)
    float* __restrict__ q0)          // (B, L, R) flat
{
    const int bid = blockIdx.x;      // = (b*NL + l)*NR + r
    const int r  = bid & 7;
    const int bl = bid >> 3;         // b*NL + l
    const int l  = bl % NL;
    const int h  = threadIdx.x;      // 0..63

    const float x = rp[l * NR + r];  // Z==1
    const float p = phi[bl];

    float h1 = fmaf(W1[h * 2 + 0], x, fmaf(W1[h * 2 + 1], p, b1[h]));
    h1 = fmaxf(h1, 0.0f);

    __shared__ float s_h1[NH];
    s_h1[h] = h1;
    __syncthreads();

    float acc = b2[h];
    const float* w2row = W2 + h * NH;
    #pragma unroll
    for (int k = 0; k < NH; ++k) acc = fmaf(w2row[k], s_h1[k], acc);
    const float h2 = fmaxf(acc, 0.0f);

    float v = W3[h] * h2;
    #pragma unroll
    for (int off = 32; off > 0; off >>= 1)
        v += __shfl_down(v, off, 64);

    if (h == 0) q0[bid] = v + b3[0];
}

// Kernel 2: out[b][n][l] = q0[b][l][(n >> 3l) & 7].
// Fill-shaped: 1536 blocks (6/CU), each thread writes 32 coalesced float4s
// over a contiguous 128KB block region; measured at the HBM write roofline.
// Every 3 consecutive float4 = 12 floats = trajectories {n=2k, 2k+1}:
//   [v0a v1 v2 v3 | v4 v5 v0b v1 | v2 v3 v4 v5]
// digits of n=2k: d0=2(k&3) (v0a=s[d0], v0b=s[d0+1]), d_l=(k>>(3l-1))&7, l>=1.
__global__ __launch_bounds__(256) void scatter_kernel(
    const float* __restrict__ q0,    // (B, L, R)
    float4* __restrict__ out4)       // (B, NTRAJ, L) viewed as float4
{
    __shared__ float s[NL * NR];     // 48 floats for this block's b
    const int b   = blockIdx.y;
    const int tid = threadIdx.x;

    if (tid < NL * NR) s[tid] = q0[b * NL * NR + tid];
    __syncthreads();

    float4* __restrict__ base = out4 + (size_t)b * F4_PER_B
                                     + (size_t)blockIdx.x * 8192;
    const unsigned ubase = blockIdx.x * 8192u + tid;

    #pragma unroll 4
    for (int j = 0; j < 32; ++j) {
        const unsigned u = ubase + j * 256u;  // float4 index within b
        const unsigned k = u / 3u;            // pair index -> n = 2k (magic-mul)
        const unsigned m = u - 3u * k;        // position in the 12-float group

        const float2 v0 = ((const float2*)s)[k & 3u];   // s[d0], s[d0+1]
        const float  v1 = s[ 8 + ((k >>  2) & 7u)];
        const float  v2 = s[16 + ((k >>  5) & 7u)];
        const float  v3 = s[24 + ((k >>  8) & 7u)];
        const float  v4 = s[32 + ((k >> 11) & 7u)];
        const float  v5 = s[40 + ((k >> 14) & 7u)];

        float4 val;
        val.x = (m == 0) ? v0.x : ((m == 1) ? v4   : v2);
        val.y = (m == 0) ? v1   : ((m == 1) ? v5   : v3);
        val.z = (m == 0) ? v2   : ((m == 1) ? v0.y : v4);
        val.w = (m == 0) ? v3   : ((m == 1) ? v1   : v5);

        base[j * 256 + tid] = val;
    }
}

extern "C" void kernel_launch(void* const* d_in, const int* in_sizes, int n_in,
                              void* d_out, int out_size, void* d_ws, size_t ws_size,
                              hipStream_t stream) {
    const float* phi = (const float*)d_in[0];  // (32, 6)
    const float* rp  = (const float*)d_in[1];  // (6, 8, 1)
    const float* W1  = (const float*)d_in[2];  // (64, 2)
    const float* b1  = (const float*)d_in[3];  // (64,)
    const float* W2  = (const float*)d_in[4];  // (64, 64)
    const float* b2  = (const float*)d_in[5];  // (64,)
    const float* W3  = (const float*)d_in[6];  // (6, 64)
    const float* b3  = (const float*)d_in[7];  // (6,)
    float* out = (float*)d_out;
    float* q0  = (float*)d_ws;                 // 1536 floats = 6 KB

    q0_kernel<<<NB * NL * NR, 64, 0, stream>>>(phi, rp, W1, b1, W2, b2, W3, b3, q0);

    dim3 grid(48, NB);
    scatter_kernel<<<grid, 256, 0, stream>>>(q0, (float4*)out);
}